// Round 4
// baseline (220.047 us; speedup 1.0000x reference)
//
#include <hip/hip_runtime.h>

// VectorQuantizer, split-bf16 MFMA, round 4: spill-free single-mtile streaming
// + cheap index-stuffed float argmin fold.
// scores = -2*E@C^T + ||c||^2; argmin_k; gather; mse losses.
//   -2e = ehi+elo (bf16 RNE), c = chi+clo; -2dot ~= ehi@chi + elo@chi + ehi@clo
// MFMA 32x32x16, D[m=codeword][n=enc_row]. Per wave: ONE codeword-tile at a
// time vs 4 enc-row tiles (acc 4x16 = 64 regs). A-frags streamed from L2 per
// k-chunk. Fold: scores quantized to 22-bit prefix, 10-bit index stuffed in
// low mantissa bits, best/second via float min/max. Any row whose observed
// top-2 gap < MARGIN gets an exact fp32 rescan (covers approx + quant error).
// Output: [0,N) idx as float | [N,N+N*D) quantized | +0,1,2 = vq,embed,commit.

#define NROWS 65536
#define KCB   1024
#define DIM   128
#define DV    32
#define MSE_DENOM 8388608.0f
#define MARGIN 1.5e-5f
#define FLAGCAP 16384

#define WS_CNORM_F 256      // float index: cnorm[1024]
#define WS_LIST_B  8192     // 16384 ints
#define WS_PH_B    73728    // 256 KB packed codebook hi frags
#define WS_PL_B    335872   // 256 KB packed codebook lo frags

typedef __attribute__((ext_vector_type(8)))  short short8;
typedef __attribute__((ext_vector_type(16))) float float16v;
typedef __attribute__((ext_vector_type(4)))  float floatx4;
union U4S8 { uint4 u; short8 s; };

__device__ __forceinline__ unsigned bf16rne(float x) {
  unsigned u = __float_as_uint(x);
  return (u + 0x7FFFu + ((u >> 16) & 1u)) >> 16;
}
__device__ __forceinline__ void split2(float y, unsigned& hb, unsigned& lb) {
  hb = bf16rne(y);
  float hf = __uint_as_float(hb << 16);
  lb = bf16rne(y - hf);
}

// ---------- prep+pack fused: blocks 0..63 pack frags, 64..67 cnorm ----------
__global__ __launch_bounds__(256) void vq_prep_pack(const float* __restrict__ C,
                                                    float* __restrict__ wsf,
                                                    uint4* __restrict__ PH,
                                                    uint4* __restrict__ PL) {
  const int b = blockIdx.x, tid = threadIdx.x;
  if (b < 64) {
    int g = b * 256 + tid;
    int mt = g >> 9, s = (g >> 6) & 7, l = g & 63;
    int cw = mt * 32 + (l & 31);
    int k0 = s * 16 + (l >> 5) * 8;
    const float* src = C + (size_t)cw * DIM + k0;
    floatx4 x0 = *(const floatx4*)src;
    floatx4 x1 = *(const floatx4*)(src + 4);
    unsigned h[8], lo[8];
    split2(x0.x, h[0], lo[0]); split2(x0.y, h[1], lo[1]);
    split2(x0.z, h[2], lo[2]); split2(x0.w, h[3], lo[3]);
    split2(x1.x, h[4], lo[4]); split2(x1.y, h[5], lo[5]);
    split2(x1.z, h[6], lo[6]); split2(x1.w, h[7], lo[7]);
    PH[g] = make_uint4(h[0] | (h[1] << 16), h[2] | (h[3] << 16),
                       h[4] | (h[5] << 16), h[6] | (h[7] << 16));
    PL[g] = make_uint4(lo[0] | (lo[1] << 16), lo[2] | (lo[3] << 16),
                       lo[4] | (lo[5] << 16), lo[6] | (lo[7] << 16));
  } else {
    int k = (b - 64) * 256 + tid;
    if (k == 0) { wsf[0] = 0.0f; ((unsigned*)wsf)[1] = 0u; }
    const floatx4* c4 = (const floatx4*)C + (size_t)k * DV;
    float s = 0.f;
#pragma unroll 8
    for (int i = 0; i < DV; ++i) {
      floatx4 v = c4[i];
      s = fmaf(v.x, v.x, s); s = fmaf(v.y, v.y, s);
      s = fmaf(v.z, v.z, s); s = fmaf(v.w, v.w, s);
    }
    wsf[WS_CNORM_F + k] = s;
  }
}

// ---------- main: MFMA sweep + argmin + loss + gather ----------
__global__ __launch_bounds__(256, 2) void vq_main4(const float* __restrict__ E,
                                                   const float* __restrict__ C,
                                                   float* __restrict__ wsf,
                                                   float* __restrict__ out) {
  __shared__ uint4  EH[2048];          // 128 rows x 16 col-chunks, frag-linear
  __shared__ uint4  EL[2048];
  __shared__ float  CN[1024];
  __shared__ float  PART[256];         // [row][half] partial ||e||^2
  __shared__ float2 M2[512];           // [wave][row] stuffed best/second
  __shared__ int    BI[128];

  const int tid  = threadIdx.x;
  const int w    = tid >> 6;
  const int l    = tid & 63;
  const int half = l >> 5;
  const int rr   = l & 31;
  const int row0 = blockIdx.x * 128;

  const uint4* PH = (const uint4*)((const char*)wsf + WS_PH_B);
  const uint4* PL = (const uint4*)((const char*)wsf + WS_PL_B);

  // ---- stage E tile (nontemporal reads; split hi/lo once per block) ----
  {
    int r = w * 32 + rr;
    const float* eb = E + (size_t)(row0 + r) * DIM + half * 64;
    float s2 = 0.f;
#pragma unroll
    for (int i = 0; i < 8; ++i) {
      floatx4 x0 = __builtin_nontemporal_load((const floatx4*)(eb + i * 8));
      floatx4 x1 = __builtin_nontemporal_load((const floatx4*)(eb + i * 8 + 4));
      s2 = fmaf(x0.x, x0.x, s2); s2 = fmaf(x0.y, x0.y, s2);
      s2 = fmaf(x0.z, x0.z, s2); s2 = fmaf(x0.w, x0.w, s2);
      s2 = fmaf(x1.x, x1.x, s2); s2 = fmaf(x1.y, x1.y, s2);
      s2 = fmaf(x1.z, x1.z, s2); s2 = fmaf(x1.w, x1.w, s2);
      unsigned h[8], lo[8];
      split2(-2.f * x0.x, h[0], lo[0]); split2(-2.f * x0.y, h[1], lo[1]);
      split2(-2.f * x0.z, h[2], lo[2]); split2(-2.f * x0.w, h[3], lo[3]);
      split2(-2.f * x1.x, h[4], lo[4]); split2(-2.f * x1.y, h[5], lo[5]);
      split2(-2.f * x1.z, h[6], lo[6]); split2(-2.f * x1.w, h[7], lo[7]);
      int a16 = w * 512 + (half * 8 + i) * 32 + rr;
      EH[a16] = make_uint4(h[0] | (h[1] << 16), h[2] | (h[3] << 16),
                           h[4] | (h[5] << 16), h[6] | (h[7] << 16));
      EL[a16] = make_uint4(lo[0] | (lo[1] << 16), lo[2] | (lo[3] << 16),
                           lo[4] | (lo[5] << 16), lo[6] | (lo[7] << 16));
    }
    PART[r * 2 + half] = s2;
    ((floatx4*)CN)[tid] = ((const floatx4*)(wsf + WS_CNORM_F))[tid];
  }
  __syncthreads();

  const float INF = __uint_as_float(0x7F800000u);
  float best[4], sec[4];
#pragma unroll
  for (int n = 0; n < 4; ++n) { best[n] = INF; sec[n] = INF; }

  // ---- sweep: wave w covers mtiles 8w..8w+7, one at a time ----
  for (int m = 0; m < 8; ++m) {
    const int mt = w * 8 + m;
    float16v acc[4];
#pragma unroll
    for (int n = 0; n < 4; ++n)
#pragma unroll
      for (int r2 = 0; r2 < 16; ++r2) acc[n][r2] = 0.f;

#pragma unroll
    for (int s = 0; s < 8; ++s) {
      U4S8 ah, al;
      ah.u = PH[(size_t)(mt * 8 + s) * 64 + l];
      al.u = PL[(size_t)(mt * 8 + s) * 64 + l];
#pragma unroll
      for (int n = 0; n < 4; ++n) {
        U4S8 bh, bl;
        bh.u = EH[n * 512 + (s * 2 + half) * 32 + rr];
        bl.u = EL[n * 512 + (s * 2 + half) * 32 + rr];
        acc[n] = __builtin_amdgcn_mfma_f32_32x32x16_bf16(ah.s, bh.s, acc[n], 0, 0, 0);
        acc[n] = __builtin_amdgcn_mfma_f32_32x32x16_bf16(al.s, bh.s, acc[n], 0, 0, 0);
        acc[n] = __builtin_amdgcn_mfma_f32_32x32x16_bf16(ah.s, bl.s, acc[n], 0, 0, 0);
      }
    }

    // fold: index-stuffed float min/max (5 VALU per score)
    const unsigned ib = (unsigned)(mt * 32 + half * 4);
#pragma unroll
    for (int reg = 0; reg < 16; ++reg) {
      const int q = reg >> 2, i2 = reg & 3;
      const unsigned idx = ib + (unsigned)(q * 8 + i2);
      const float cn = CN[mt * 32 + q * 8 + half * 4 + i2];
#pragma unroll
      for (int n = 0; n < 4; ++n) {
        float sc = acc[n][reg] + cn;
        float uf = __uint_as_float((__float_as_uint(sc) & 0xFFFFFC00u) | idx);
        float nb = fminf(best[n], uf);
        sec[n]  = fminf(sec[n], fmaxf(best[n], uf));
        best[n] = nb;
      }
    }
  }

  // ---- merge halves, stash per-wave results ----
#pragma unroll
  for (int n = 0; n < 4; ++n) {
    float b = best[n], s = sec[n];
    float ob = __shfl_xor(b, 32, 64);
    float os = __shfl_xor(s, 32, 64);
    float nb = fminf(b, ob);
    float ns = fminf(fminf(s, os), fmaxf(b, ob));
    if (half == 0) M2[w * 128 + n * 32 + rr] = make_float2(nb, ns);
  }
  __syncthreads();

  // ---- final per-row: merge 4 waves, flag, loss, index ----
  if (tid < 128) {
    const int r = tid;
    float2 p0 = M2[r];
    float b = p0.x, s = p0.y;
#pragma unroll
    for (int ww = 1; ww < 4; ++ww) {
      float2 p = M2[ww * 128 + r];
      s = fminf(fminf(s, p.y), fmaxf(b, p.x));
      b = fminf(b, p.x);
    }
    int bi = (int)(__float_as_uint(b) & 1023u);
    out[row0 + r] = (float)bi;
    BI[r] = bi;
    if (s - b < MARGIN) {
      unsigned idx = atomicAdd((unsigned*)wsf + 1, 1u);
      if (idx < FLAGCAP) ((int*)((char*)wsf + WS_LIST_B))[idx] = row0 + r;
    }
    float term = PART[r * 2] + PART[r * 2 + 1] + b;
#pragma unroll
    for (int off = 32; off > 0; off >>= 1) term += __shfl_down(term, off);
    if ((tid & 63) == 0) atomicAdd(wsf, term);
  }
  __syncthreads();

  // ---- gather quantized_st (C rows L2-hot; nontemporal stores) ----
  const floatx4* C4   = (const floatx4*)C;
  floatx4*       out4 = (floatx4*)out;
#pragma unroll
  for (int it = 0; it < 16; ++it) {
    int flat = it * 256 + tid;
    int r = flat >> 5, d4 = flat & 31;
    floatx4 v = C4[(size_t)BI[r] * DV + d4];
    __builtin_nontemporal_store(v, &out4[(NROWS / 4) + (size_t)(row0 + r) * DV + d4]);
  }
}

// ---------- exact fp32 rescan of flagged rows (4 rows per C-sweep) ----------
__global__ __launch_bounds__(256) void vq_fix(const float* __restrict__ E,
                                              const float* __restrict__ C,
                                              float* __restrict__ wsf,
                                              float* __restrict__ out) {
  __shared__ floatx4 eL[4][32];
  __shared__ float   sv[4][256];
  __shared__ int     si[4][256];
  __shared__ int     RESi[4];
  const int tid = threadIdx.x;
  if (blockIdx.x == 0 && tid == 0) {
    float mse = wsf[0] / MSE_DENOM;
    out[NROWS + NROWS * DIM + 0] = 1.25f * mse;
    out[NROWS + NROWS * DIM + 1] = mse;
    out[NROWS + NROWS * DIM + 2] = mse;
  }
  const int* list = (const int*)((const char*)wsf + WS_LIST_B);
  int nf = (int)((const unsigned*)wsf)[1];
  if (nf > FLAGCAP) nf = FLAGCAP;
  const floatx4* E4 = (const floatx4*)E;
  const floatx4* C4 = (const floatx4*)C;
  const float*   cn = wsf + WS_CNORM_F;
  floatx4* out4 = (floatx4*)out;

  for (int base = blockIdx.x * 4; base < nf; base += gridDim.x * 4) {
    int rg[4];
#pragma unroll
    for (int j = 0; j < 4; ++j) {
      int ii = base + j; if (ii >= nf) ii = nf - 1;
      rg[j] = list[ii];
    }
    if (tid < 128) {
      int j = tid >> 5, d4 = tid & 31;
      eL[j][d4] = E4[(size_t)rg[j] * DV + d4];
    }
    __syncthreads();
    float bv[4]; int bi[4];
#pragma unroll
    for (int r = 0; r < 4; ++r) { bv[r] = 3.0e38f; bi[r] = 0; }
#pragma unroll
    for (int jj = 0; jj < 4; ++jj) {
      int k = jj * 256 + tid;
      float d[4] = {0.f, 0.f, 0.f, 0.f};
#pragma unroll 8
      for (int d4 = 0; d4 < 32; ++d4) {
        floatx4 c = C4[(size_t)k * DV + d4];
#pragma unroll
        for (int r = 0; r < 4; ++r) {
          floatx4 e = eL[r][d4];
          d[r] = fmaf(c.x, e.x, d[r]); d[r] = fmaf(c.y, e.y, d[r]);
          d[r] = fmaf(c.z, e.z, d[r]); d[r] = fmaf(c.w, e.w, d[r]);
        }
      }
      float cnk = cn[k];
#pragma unroll
      for (int r = 0; r < 4; ++r) {
        float s = fmaf(-2.f, d[r], cnk);
        if (s < bv[r] || (s == bv[r] && k < bi[r])) { bv[r] = s; bi[r] = k; }
      }
    }
#pragma unroll
    for (int r = 0; r < 4; ++r) { sv[r][tid] = bv[r]; si[r][tid] = bi[r]; }
    __syncthreads();
    if (tid < 128) {
      const int r = tid >> 5, ln = tid & 31;
      float v = sv[r][ln]; int i0 = si[r][ln];
#pragma unroll
      for (int q = 1; q < 8; ++q) {
        float v2 = sv[r][ln + q * 32]; int j2 = si[r][ln + q * 32];
        if (v2 < v || (v2 == v && j2 < i0)) { v = v2; i0 = j2; }
      }
#pragma unroll
      for (int off = 16; off > 0; off >>= 1) {
        float v2 = __shfl_down(v, off, 32); int j2 = __shfl_down(i0, off, 32);
        if (v2 < v || (v2 == v && j2 < i0)) { v = v2; i0 = j2; }
      }
      if (ln == 0) { RESi[r] = i0; out[rg[r]] = (float)i0; }
    }
    __syncthreads();
    if (tid < 128) {
      int j = tid >> 5, d4 = tid & 31;
      out4[(NROWS / 4) + (size_t)rg[j] * DV + d4] = C4[(size_t)RESi[j] * DV + d4];
    }
    __syncthreads();
  }
}

extern "C" void kernel_launch(void* const* d_in, const int* in_sizes, int n_in,
                              void* d_out, int out_size, void* d_ws, size_t ws_size,
                              hipStream_t stream) {
  const float* E = (const float*)d_in[0];
  const float* C = (const float*)d_in[1];
  float* out = (float*)d_out;
  float* wsf = (float*)d_ws;
  uint4* PH = (uint4*)((char*)d_ws + WS_PH_B);
  uint4* PL = (uint4*)((char*)d_ws + WS_PL_B);

  vq_prep_pack<<<68, 256, 0, stream>>>(C, wsf, PH, PL);
  vq_main4<<<NROWS / 128, 256, 0, stream>>>(E, C, wsf, out);
  vq_fix<<<256, 256, 0, stream>>>(E, C, wsf, out);
}

// Round 5
// 218.633 us; speedup vs baseline: 1.0065x; 1.0065x over previous
//
#include <hip/hip_runtime.h>

// VectorQuantizer, split-bf16 MFMA, round 5.
// Key change vs r4: packed codebook fragments (PH/PL) + cnorm live in the
// TAIL of d_out's quantized region (cacheable memory) instead of d_ws, which
// behaves uncached (r2-r4: FETCH ~= full PH/PL re-read from memory per block).
// The 2048 tail rows' quantized writes are deferred to vq_fix (kernel-boundary
// ordering); their argmin indices ride through ws.
//   -2e = ehi+elo (bf16 RNE), c = chi+clo; -2dot ~= ehi@chi + elo@chi + ehi@clo
// MFMA 32x32x16, D[m=codeword][n=enc_row]; acc 4x16 = 64 regs per wave.
// Rows with observed top-2 gap < MARGIN get exact fp32 rescan in vq_fix.
// Output: [0,N) idx as float | [N,N+N*D) quantized | +0,1,2 = vq,embed,commit.

#define NROWS 65536
#define KCB   1024
#define DIM   128
#define DV    32
#define MSE_DENOM 8388608.0f
#define MARGIN 1.5e-5f
#define FLAGCAP 16384
#define DEFER0 63488                 // 496*128: rows whose gather is deferred
#define NDEFER 2048

// d_out tail scratch (float indices into out)
#define OUT_PH_F 8192000             // = NROWS + DEFER0*DIM; 256 KB of PH
#define OUT_PL_F 8257536             // 256 KB of PL
#define OUT_CN_F 8323072             // 4 KB cnorm

// ws layout: [0]=loss, [1]=nflag; cnorm floats [256,1280);
// BI_tail ints [2048,4096); flags ints [4096,6144); list ints at byte 32768.
#define WS_CNORM_F  256
#define WS_BITAIL_I 2048
#define WS_FLAG_I   4096
#define WS_LIST_B   32768

typedef __attribute__((ext_vector_type(8)))  short short8;
typedef __attribute__((ext_vector_type(16))) float float16v;
typedef __attribute__((ext_vector_type(4)))  float floatx4;
union U4S8 { uint4 u; short8 s; };

__device__ __forceinline__ unsigned bf16rne(float x) {
  unsigned u = __float_as_uint(x);
  return (u + 0x7FFFu + ((u >> 16) & 1u)) >> 16;
}
__device__ __forceinline__ void split2(float y, unsigned& hb, unsigned& lb) {
  hb = bf16rne(y);
  float hf = __uint_as_float(hb << 16);
  lb = bf16rne(y - hf);
}

// ---------- prep+pack: blocks 0..63 pack frags into OUT tail; 64..67 cnorm ----------
__global__ __launch_bounds__(256) void vq_prep_pack(const float* __restrict__ C,
                                                    float* __restrict__ wsf,
                                                    float* __restrict__ out) {
  const int b = blockIdx.x, tid = threadIdx.x;
  if (b < 64) {
    uint4* PH = (uint4*)(out + OUT_PH_F);
    uint4* PL = (uint4*)(out + OUT_PL_F);
    int g = b * 256 + tid;
    int mt = g >> 9, s = (g >> 6) & 7, l = g & 63;
    int cw = mt * 32 + (l & 31);
    int k0 = s * 16 + (l >> 5) * 8;
    const float* src = C + (size_t)cw * DIM + k0;
    floatx4 x0 = *(const floatx4*)src;
    floatx4 x1 = *(const floatx4*)(src + 4);
    unsigned h[8], lo[8];
    split2(x0.x, h[0], lo[0]); split2(x0.y, h[1], lo[1]);
    split2(x0.z, h[2], lo[2]); split2(x0.w, h[3], lo[3]);
    split2(x1.x, h[4], lo[4]); split2(x1.y, h[5], lo[5]);
    split2(x1.z, h[6], lo[6]); split2(x1.w, h[7], lo[7]);
    PH[g] = make_uint4(h[0] | (h[1] << 16), h[2] | (h[3] << 16),
                       h[4] | (h[5] << 16), h[6] | (h[7] << 16));
    PL[g] = make_uint4(lo[0] | (lo[1] << 16), lo[2] | (lo[3] << 16),
                       lo[4] | (lo[5] << 16), lo[6] | (lo[7] << 16));
  } else {
    int k = (b - 64) * 256 + tid;     // 0..1023
    if (k == 0) { wsf[0] = 0.0f; ((unsigned*)wsf)[1] = 0u; }
    ((int*)wsf)[WS_FLAG_I + k] = 0;
    ((int*)wsf)[WS_FLAG_I + k + 1024] = 0;
    const floatx4* c4 = (const floatx4*)C + (size_t)k * DV;
    float s = 0.f;
#pragma unroll 8
    for (int i = 0; i < DV; ++i) {
      floatx4 v = c4[i];
      s = fmaf(v.x, v.x, s); s = fmaf(v.y, v.y, s);
      s = fmaf(v.z, v.z, s); s = fmaf(v.w, v.w, s);
    }
    wsf[WS_CNORM_F + k] = s;          // copy for vq_fix (ws)
    out[OUT_CN_F + k]   = s;          // copy for vq_main (cacheable)
  }
}

// ---------- main: MFMA sweep + argmin + loss + gather ----------
__global__ __launch_bounds__(256, 2) void vq_main5(const float* __restrict__ E,
                                                   const float* __restrict__ C,
                                                   float* __restrict__ wsf,
                                                   float* __restrict__ out) {
  __shared__ uint4  EH[2048];          // 128 rows x 16 col-chunks, frag-linear
  __shared__ uint4  EL[2048];
  __shared__ float  CN[1024];
  __shared__ float  PART[256];         // [row][half] partial ||e||^2
  __shared__ float2 M2[512];           // [wave][row] stuffed best/second
  __shared__ int    BI[128];

  const int tid  = threadIdx.x;
  const int w    = tid >> 6;
  const int l    = tid & 63;
  const int half = l >> 5;
  const int rr   = l & 31;
  const int row0 = blockIdx.x * 128;

  const uint4* PH = (const uint4*)(out + OUT_PH_F);
  const uint4* PL = (const uint4*)(out + OUT_PL_F);

  // ---- stage E tile (nontemporal reads; split hi/lo once per block) ----
  {
    int r = w * 32 + rr;
    const float* eb = E + (size_t)(row0 + r) * DIM + half * 64;
    float s2 = 0.f;
#pragma unroll
    for (int i = 0; i < 8; ++i) {
      floatx4 x0 = __builtin_nontemporal_load((const floatx4*)(eb + i * 8));
      floatx4 x1 = __builtin_nontemporal_load((const floatx4*)(eb + i * 8 + 4));
      s2 = fmaf(x0.x, x0.x, s2); s2 = fmaf(x0.y, x0.y, s2);
      s2 = fmaf(x0.z, x0.z, s2); s2 = fmaf(x0.w, x0.w, s2);
      s2 = fmaf(x1.x, x1.x, s2); s2 = fmaf(x1.y, x1.y, s2);
      s2 = fmaf(x1.z, x1.z, s2); s2 = fmaf(x1.w, x1.w, s2);
      unsigned h[8], lo[8];
      split2(-2.f * x0.x, h[0], lo[0]); split2(-2.f * x0.y, h[1], lo[1]);
      split2(-2.f * x0.z, h[2], lo[2]); split2(-2.f * x0.w, h[3], lo[3]);
      split2(-2.f * x1.x, h[4], lo[4]); split2(-2.f * x1.y, h[5], lo[5]);
      split2(-2.f * x1.z, h[6], lo[6]); split2(-2.f * x1.w, h[7], lo[7]);
      int a16 = w * 512 + (half * 8 + i) * 32 + rr;
      EH[a16] = make_uint4(h[0] | (h[1] << 16), h[2] | (h[3] << 16),
                           h[4] | (h[5] << 16), h[6] | (h[7] << 16));
      EL[a16] = make_uint4(lo[0] | (lo[1] << 16), lo[2] | (lo[3] << 16),
                           lo[4] | (lo[5] << 16), lo[6] | (lo[7] << 16));
    }
    PART[r * 2 + half] = s2;
    ((floatx4*)CN)[tid] = ((const floatx4*)(out + OUT_CN_F))[tid];
  }
  __syncthreads();

  const float INF = __uint_as_float(0x7F800000u);
  float best[4], sec[4];
#pragma unroll
  for (int n = 0; n < 4; ++n) { best[n] = INF; sec[n] = INF; }

  // ---- sweep: wave w covers mtiles 8w..8w+7, one at a time ----
  for (int m = 0; m < 8; ++m) {
    const int mt = w * 8 + m;
    float16v acc[4];
#pragma unroll
    for (int n = 0; n < 4; ++n)
#pragma unroll
      for (int r2 = 0; r2 < 16; ++r2) acc[n][r2] = 0.f;

#pragma unroll
    for (int s = 0; s < 8; ++s) {
      U4S8 ah, al;
      ah.u = PH[(size_t)(mt * 8 + s) * 64 + l];
      al.u = PL[(size_t)(mt * 8 + s) * 64 + l];
#pragma unroll
      for (int n = 0; n < 4; ++n) {
        U4S8 bh, bl;
        bh.u = EH[n * 512 + (s * 2 + half) * 32 + rr];
        bl.u = EL[n * 512 + (s * 2 + half) * 32 + rr];
        acc[n] = __builtin_amdgcn_mfma_f32_32x32x16_bf16(ah.s, bh.s, acc[n], 0, 0, 0);
        acc[n] = __builtin_amdgcn_mfma_f32_32x32x16_bf16(al.s, bh.s, acc[n], 0, 0, 0);
        acc[n] = __builtin_amdgcn_mfma_f32_32x32x16_bf16(ah.s, bl.s, acc[n], 0, 0, 0);
      }
    }

    // fold: index-stuffed float min/max
    const unsigned ib = (unsigned)(mt * 32 + half * 4);
#pragma unroll
    for (int reg = 0; reg < 16; ++reg) {
      const int q = reg >> 2, i2 = reg & 3;
      const unsigned idx = ib + (unsigned)(q * 8 + i2);
      const float cn = CN[mt * 32 + q * 8 + half * 4 + i2];
#pragma unroll
      for (int n = 0; n < 4; ++n) {
        float sc = acc[n][reg] + cn;
        float uf = __uint_as_float((__float_as_uint(sc) & 0xFFFFFC00u) | idx);
        float nb = fminf(best[n], uf);
        sec[n]  = fminf(sec[n], fmaxf(best[n], uf));
        best[n] = nb;
      }
    }
  }

  // ---- merge halves, stash per-wave results ----
#pragma unroll
  for (int n = 0; n < 4; ++n) {
    float b = best[n], s = sec[n];
    float ob = __shfl_xor(b, 32, 64);
    float os = __shfl_xor(s, 32, 64);
    float nb = fminf(b, ob);
    float ns = fminf(fminf(s, os), fmaxf(b, ob));
    if (half == 0) M2[w * 128 + n * 32 + rr] = make_float2(nb, ns);
  }
  __syncthreads();

  // ---- final per-row: merge 4 waves, flag, loss, index ----
  if (tid < 128) {
    const int r = tid;
    float2 p0 = M2[r];
    float b = p0.x, s = p0.y;
#pragma unroll
    for (int ww = 1; ww < 4; ++ww) {
      float2 p = M2[ww * 128 + r];
      s = fminf(fminf(s, p.y), fmaxf(b, p.x));
      b = fminf(b, p.x);
    }
    int bi = (int)(__float_as_uint(b) & 1023u);
    out[row0 + r] = (float)bi;
    BI[r] = bi;
    if (s - b < MARGIN) {
      unsigned idx = atomicAdd((unsigned*)wsf + 1, 1u);
      if (idx < FLAGCAP) {
        ((int*)((char*)wsf + WS_LIST_B))[idx] = row0 + r;
        if (row0 >= DEFER0) ((int*)wsf)[WS_FLAG_I + (row0 - DEFER0) + r] = 1;
      }
    }
    float term = PART[r * 2] + PART[r * 2 + 1] + b;
#pragma unroll
    for (int off = 32; off > 0; off >>= 1) term += __shfl_down(term, off);
    if ((tid & 63) == 0) atomicAdd(wsf, term);
  }
  __syncthreads();

  if (row0 >= DEFER0) {
    // deferred rows: frag region still live — record indices, gather in vq_fix
    if (tid < 128) ((int*)wsf)[WS_BITAIL_I + (row0 - DEFER0) + tid] = BI[tid];
  } else {
    const floatx4* C4   = (const floatx4*)C;
    floatx4*       out4 = (floatx4*)out;
#pragma unroll
    for (int it = 0; it < 16; ++it) {
      int flat = it * 256 + tid;
      int r = flat >> 5, d4 = flat & 31;
      floatx4 v = C4[(size_t)BI[r] * DV + d4];
      __builtin_nontemporal_store(v, &out4[(NROWS / 4) + (size_t)(row0 + r) * DV + d4]);
    }
  }
}

// ---------- vq_fix: deferred tail gather + exact fp32 rescan + scalars ----------
__global__ __launch_bounds__(256) void vq_fix(const float* __restrict__ E,
                                              const float* __restrict__ C,
                                              float* __restrict__ wsf,
                                              float* __restrict__ out) {
  __shared__ floatx4 eL[4][32];
  __shared__ float   sv[4][256];
  __shared__ int     si[4][256];
  __shared__ int     RESi[4];
  const int tid = threadIdx.x;
  const floatx4* E4 = (const floatx4*)E;
  const floatx4* C4 = (const floatx4*)C;
  floatx4* out4 = (floatx4*)out;

  if (blockIdx.x == 0 && tid == 0) {
    float mse = wsf[0] / MSE_DENOM;
    out[NROWS + NROWS * DIM + 0] = 1.25f * mse;
    out[NROWS + NROWS * DIM + 1] = mse;
    out[NROWS + NROWS * DIM + 2] = mse;
  }

  // stage 1: gather deferred tail rows (unflagged); grid 256 x 8 rows = 2048
  {
    int j = tid >> 5, d4 = tid & 31;
    int dr = blockIdx.x * 8 + j;
    if (((const int*)wsf)[WS_FLAG_I + dr] == 0) {
      int bi = ((const int*)wsf)[WS_BITAIL_I + dr];
      out4[(NROWS / 4) + (size_t)(DEFER0 + dr) * DV + d4] = C4[(size_t)bi * DV + d4];
    }
  }

  // stage 2: exact rescan of flagged rows, 4 per C-sweep
  const int* list = (const int*)((const char*)wsf + WS_LIST_B);
  int nf = (int)((const unsigned*)wsf)[1];
  if (nf > FLAGCAP) nf = FLAGCAP;
  const float* cn = wsf + WS_CNORM_F;

  for (int base = blockIdx.x * 4; base < nf; base += gridDim.x * 4) {
    int rg[4];
#pragma unroll
    for (int j = 0; j < 4; ++j) {
      int ii = base + j; if (ii >= nf) ii = nf - 1;
      rg[j] = list[ii];
    }
    if (tid < 128) {
      int j = tid >> 5, d4 = tid & 31;
      eL[j][d4] = E4[(size_t)rg[j] * DV + d4];
    }
    __syncthreads();
    float bv[4]; int bi[4];
#pragma unroll
    for (int r = 0; r < 4; ++r) { bv[r] = 3.0e38f; bi[r] = 0; }
#pragma unroll
    for (int jj = 0; jj < 4; ++jj) {
      int k = jj * 256 + tid;
      float d[4] = {0.f, 0.f, 0.f, 0.f};
#pragma unroll 8
      for (int d4 = 0; d4 < 32; ++d4) {
        floatx4 c = C4[(size_t)k * DV + d4];
#pragma unroll
        for (int r = 0; r < 4; ++r) {
          floatx4 e = eL[r][d4];
          d[r] = fmaf(c.x, e.x, d[r]); d[r] = fmaf(c.y, e.y, d[r]);
          d[r] = fmaf(c.z, e.z, d[r]); d[r] = fmaf(c.w, e.w, d[r]);
        }
      }
      float cnk = cn[k];
#pragma unroll
      for (int r = 0; r < 4; ++r) {
        float s = fmaf(-2.f, d[r], cnk);
        if (s < bv[r] || (s == bv[r] && k < bi[r])) { bv[r] = s; bi[r] = k; }
      }
    }
#pragma unroll
    for (int r = 0; r < 4; ++r) { sv[r][tid] = bv[r]; si[r][tid] = bi[r]; }
    __syncthreads();
    if (tid < 128) {
      const int r = tid >> 5, ln = tid & 31;
      float v = sv[r][ln]; int i0 = si[r][ln];
#pragma unroll
      for (int q = 1; q < 8; ++q) {
        float v2 = sv[r][ln + q * 32]; int j2 = si[r][ln + q * 32];
        if (v2 < v || (v2 == v && j2 < i0)) { v = v2; i0 = j2; }
      }
#pragma unroll
      for (int off = 16; off > 0; off >>= 1) {
        float v2 = __shfl_down(v, off, 32); int j2 = __shfl_down(i0, off, 32);
        if (v2 < v || (v2 == v && j2 < i0)) { v = v2; i0 = j2; }
      }
      if (ln == 0) { RESi[r] = i0; out[rg[r]] = (float)i0; }
    }
    __syncthreads();
    if (tid < 128) {
      int j = tid >> 5, d4 = tid & 31;
      out4[(NROWS / 4) + (size_t)rg[j] * DV + d4] = C4[(size_t)RESi[j] * DV + d4];
    }
    __syncthreads();
  }
}

extern "C" void kernel_launch(void* const* d_in, const int* in_sizes, int n_in,
                              void* d_out, int out_size, void* d_ws, size_t ws_size,
                              hipStream_t stream) {
  const float* E = (const float*)d_in[0];
  const float* C = (const float*)d_in[1];
  float* out = (float*)d_out;
  float* wsf = (float*)d_ws;

  vq_prep_pack<<<68, 256, 0, stream>>>(C, wsf, out);
  vq_main5<<<NROWS / 128, 256, 0, stream>>>(E, C, wsf, out);
  vq_fix<<<256, 256, 0, stream>>>(E, C, wsf, out);
}